// Round 6
// baseline (161.207 us; speedup 1.0000x reference)
//
#include <hip/hip_runtime.h>

// LSTMClassifier: B=1024, T=1024, H=16, C=6
// One wave per batch (1024 waves = 1/SIMD = max parallelism). Lane 4j+q owns
// gate q of hidden unit j. Pure latency/issue-bound serial recurrence.
//  - matvec: h as f16 pairs, 8 readlane + 8 v_dot2_f32_f16 in a 4-chain tree
//  - front-end: ROW_ROR:8 partner + one v_cvt_pkrtz_f16_f32 pack
//  - kk folded into weights; cell state pre-scaled cs = -2*log2e*c
//  - cs path: cs = fma(r1, cs, fma(m2, r2, -m)), m/m2 issue in DPP shadow

#define T_LEN 1024
#define BATCH 1024

typedef _Float16 h2v __attribute__((ext_vector_type(2)));

__device__ __forceinline__ float rlanef(float v, int l) {
    return __int_as_float(__builtin_amdgcn_readlane(__float_as_int(v), l));
}
__device__ __forceinline__ int rlanei(int v, int l) {
    return __builtin_amdgcn_readlane(v, l);
}

template<int CTRL>
__device__ __forceinline__ float movdpp(float v) {
    return __int_as_float(
        __builtin_amdgcn_mov_dpp(__float_as_int(v), CTRL, 0xf, 0xf, true));
}

template<int N>
__device__ __forceinline__ float quad_bcastf(float v) {
    constexpr int ctrl = N * 0x55;  // replicate lane N of each quad
    return __int_as_float(
        __builtin_amdgcn_mov_dpp(__float_as_int(v), ctrl, 0xf, 0xf, true));
}

__device__ __forceinline__ float fexp2(float x) {
#if __has_builtin(__builtin_amdgcn_exp2f)
    return __builtin_amdgcn_exp2f(x);
#else
    return exp2f(x);
#endif
}
__device__ __forceinline__ float frcp(float x) {
#if __has_builtin(__builtin_amdgcn_rcpf)
    return __builtin_amdgcn_rcpf(x);
#else
    return 1.0f / x;
#endif
}

__device__ __forceinline__ float fdot2(h2v a, h2v b, float c) {
#if __has_builtin(__builtin_amdgcn_fdot2)
    return __builtin_amdgcn_fdot2(a, b, c, false);
#else
    return fmaf((float)a.x, (float)b.x, fmaf((float)a.y, (float)b.y, c));
#endif
}

__device__ __forceinline__ int pack_rtz(float lo, float hi) {
#if __has_builtin(__builtin_amdgcn_cvt_pkrtz)
    return __builtin_bit_cast(int, __builtin_amdgcn_cvt_pkrtz(lo, hi));
#else
    h2v p; p.x = (_Float16)lo; p.y = (_Float16)hi;
    return __builtin_bit_cast(int, p);
#endif
}

__device__ __forceinline__ h2v as_h2(int bits) {
    return __builtin_bit_cast(h2v, bits);
}

__launch_bounds__(256)
__global__ void lstm_cls_kernel(const float* __restrict__ x,
                                const float* __restrict__ W_ih,
                                const float* __restrict__ W_hh,
                                const float* __restrict__ b_ih,
                                const float* __restrict__ b_hh,
                                const float* __restrict__ W_fc,
                                const float* __restrict__ b_fc,
                                float* __restrict__ out) {
    const int tid  = threadIdx.x;
    const int wave = tid >> 6;
    const int lane = tid & 63;
    const int b    = blockIdx.x * 4 + wave;   // one batch per wave
    const int j    = lane >> 2;               // hidden unit 0..15
    const int q    = lane & 3;                // 0=i, 1=f, 2=g, 3=o
    const int row  = q * 16 + j;              // row in [4H] (PyTorch order)

    const float LOG2E = 1.44269504088896340736f;
    const float NEG2L = -2.0f * LOG2E;
    const float NEG4L = -4.0f * LOG2E;
    // kk folded into weights: matvec emits kk*a; r = 1/(1+exp2(kk*a))
    // q!=2 -> sigmoid(a); q==2 -> (tanh(a)+1)/2
    const float kk = (q == 2) ? NEG2L : -LOG2E;

    // f16 weight pairs matching the h-pair pattern (k0, k0+2):
    // (0,2)(1,3)(4,6)(5,7)(8,10)(9,11)(12,14)(13,15)
    const float* wr = W_hh + row * 16;
    h2v wp0, wp1, wp2, wp3, wp4, wp5, wp6, wp7;
    {
        #define MKWP(WP, K0) \
            WP.x = (_Float16)(kk * wr[K0]); WP.y = (_Float16)(kk * wr[(K0) + 2]);
        MKWP(wp0, 0) MKWP(wp1, 1) MKWP(wp2, 4) MKWP(wp3, 5)
        MKWP(wp4, 8) MKWP(wp5, 9) MKWP(wp6, 12) MKWP(wp7, 13)
        #undef MKWP
    }

    const float kwih  = kk * W_ih[row];
    const float kbias = kk * (b_ih[row] + b_hh[row]);

    // Preload the wave's x sequence into 16 VGPRs
    const float4* xv = (const float4*)(x + (size_t)b * T_LEN);
    const float4 xq0 = xv[lane];
    const float4 xq1 = xv[lane + 64];
    const float4 xq2 = xv[lane + 128];
    const float4 xq3 = xv[lane + 192];

    float h  = 0.0f;
    float cs = 0.0f;   // cs = -2*log2e * c  (pre-scaled cell state)

    auto step = [&](float xs) {
        const float ax = fmaf(kwih, xs, kbias);

        // (h_j, h_{j+-2}) f16 pair: partner via ROW_ROR:8, pack with pkrtz
        const float hr = movdpp<0x128>(h);
        const int hb = pack_rtz(h, hr);

        // q=0 source lanes: 0->(h0,h2) 4->(h1,h3) 16->(h4,h6) 20->(h5,h7)
        //                   32->(h8,h10) 36->(h9,h11) 48->(h12,h14) 52->(h13,h15)
        const int s0 = rlanei(hb, 0);
        const int s1 = rlanei(hb, 4);
        const int s2 = rlanei(hb, 16);
        const int s3 = rlanei(hb, 20);
        const int s4 = rlanei(hb, 32);
        const int s5 = rlanei(hb, 36);
        const int s6 = rlanei(hb, 48);
        const int s7 = rlanei(hb, 52);

        // 4 chains of depth 2 + 2-level add tree (shorter critical path)
        float A = fdot2(wp0, as_h2(s0), ax);
        float B = fdot2(wp1, as_h2(s1), 0.0f);
        float C = fdot2(wp2, as_h2(s2), 0.0f);
        float D = fdot2(wp3, as_h2(s3), 0.0f);
        A = fdot2(wp4, as_h2(s4), A);
        B = fdot2(wp5, as_h2(s5), B);
        C = fdot2(wp6, as_h2(s6), C);
        D = fdot2(wp7, as_h2(s7), D);
        const float sa = (A + B) + (C + D);   // = kk * a_row

        const float r = frcp(1.0f + fexp2(sa));

        // quad gather (r0 = self; only q=0 lanes' h/cs are ever read)
        const float r1 = quad_bcastf<1>(r);   // f (sigmoid)
        const float r2 = quad_bcastf<2>(r);   // (tanh g + 1)/2
        const float r3 = quad_bcastf<3>(r);   // o (sigmoid)

        // cs = r1*cs + NEG2L*r*(2*r2-1) = fma(r1, cs, fma(m2, r2, -m))
        const float m  = NEG2L * r;           // DPP shadow
        const float m2 = NEG4L * r;           // DPP shadow
        const float term = fmaf(m2, r2, -m);
        cs = fmaf(r1, cs, term);              // cs = -2L * c

        // h = o*tanh(c) = 2*o/(1+exp2(cs)) - o
        const float et = fexp2(cs);
        const float rt = frcp(1.0f + et);
        const float t3 = r3 + r3;             // exp shadow
        h = fmaf(t3, rt, -r3);
    };

    #pragma unroll
    for (int k = 0; k < 4; ++k) {
        const float4 xk = (k == 0) ? xq0 : (k == 1) ? xq1
                        : (k == 2) ? xq2 : xq3;
        #pragma unroll 4
        for (int r = 0; r < 64; ++r) {
            step(rlanef(xk.x, r));
            step(rlanef(xk.y, r));
            step(rlanef(xk.z, r));
            step(rlanef(xk.w, r));
        }
    }

    // Epilogue: logits[b, cc] = b_fc[cc] + sum_k W_fc[cc,k] * h_k
    float hv[16];
    #pragma unroll
    for (int k = 0; k < 16; ++k) hv[k] = rlanef(h, 4 * k);

    if (lane < 6) {
        const float* wf = W_fc + lane * 16;
        float acc = b_fc[lane];
        #pragma unroll
        for (int k = 0; k < 16; ++k) acc = fmaf(wf[k], hv[k], acc);
        out[b * 6 + lane] = acc;
    }
}

extern "C" void kernel_launch(void* const* d_in, const int* in_sizes, int n_in,
                              void* d_out, int out_size, void* d_ws, size_t ws_size,
                              hipStream_t stream) {
    const float* x    = (const float*)d_in[0];
    const float* W_ih = (const float*)d_in[1];
    const float* W_hh = (const float*)d_in[2];
    const float* b_ih = (const float*)d_in[3];
    const float* b_hh = (const float*)d_in[4];
    const float* W_fc = (const float*)d_in[5];
    const float* b_fc = (const float*)d_in[6];
    float* out = (float*)d_out;

    lstm_cls_kernel<<<BATCH / 4, 256, 0, stream>>>(x, W_ih, W_hh, b_ih, b_hh,
                                                   W_fc, b_fc, out);
}

// Round 7
// 156.704 us; speedup vs baseline: 1.0287x; 1.0287x over previous
//
#include <hip/hip_runtime.h>

// LSTMClassifier: B=1024, T=1024, H=16, C=6
// One wave per batch (1024 waves = 1/SIMD = max parallelism). Lane 4j+q owns
// gate q of hidden unit j. Pure latency/issue-bound serial recurrence.
//  - matvec: h as f16 pairs, 8 readlane + 8 v_dot2_f32_f16, two 4-deep chains
//  - front-end: ROW_ROR:8 partner + one v_cvt_pkrtz_f16_f32 pack
//  - kk folded into weights; cell state pre-scaled cs = -2*log2e*c
//  - x contribution (ax) hoisted per 4-step group: off the serial chain
// R6 lesson: 4-chain tree + unroll-4 regressed (more issue, worse sched);
// this is R5's shape + ax hoist only.

#define T_LEN 1024
#define BATCH 1024

typedef _Float16 h2v __attribute__((ext_vector_type(2)));

__device__ __forceinline__ float rlanef(float v, int l) {
    return __int_as_float(__builtin_amdgcn_readlane(__float_as_int(v), l));
}
__device__ __forceinline__ int rlanei(int v, int l) {
    return __builtin_amdgcn_readlane(v, l);
}

template<int CTRL>
__device__ __forceinline__ float movdpp(float v) {
    return __int_as_float(
        __builtin_amdgcn_mov_dpp(__float_as_int(v), CTRL, 0xf, 0xf, true));
}

template<int N>
__device__ __forceinline__ float quad_bcastf(float v) {
    constexpr int ctrl = N * 0x55;  // replicate lane N of each quad
    return __int_as_float(
        __builtin_amdgcn_mov_dpp(__float_as_int(v), ctrl, 0xf, 0xf, true));
}

__device__ __forceinline__ float fexp2(float x) {
#if __has_builtin(__builtin_amdgcn_exp2f)
    return __builtin_amdgcn_exp2f(x);
#else
    return exp2f(x);
#endif
}
__device__ __forceinline__ float frcp(float x) {
#if __has_builtin(__builtin_amdgcn_rcpf)
    return __builtin_amdgcn_rcpf(x);
#else
    return 1.0f / x;
#endif
}

__device__ __forceinline__ float fdot2(h2v a, h2v b, float c) {
#if __has_builtin(__builtin_amdgcn_fdot2)
    return __builtin_amdgcn_fdot2(a, b, c, false);
#else
    return fmaf((float)a.x, (float)b.x, fmaf((float)a.y, (float)b.y, c));
#endif
}

__device__ __forceinline__ int pack_rtz(float lo, float hi) {
#if __has_builtin(__builtin_amdgcn_cvt_pkrtz)
    return __builtin_bit_cast(int, __builtin_amdgcn_cvt_pkrtz(lo, hi));
#else
    h2v p; p.x = (_Float16)lo; p.y = (_Float16)hi;
    return __builtin_bit_cast(int, p);
#endif
}

__device__ __forceinline__ h2v as_h2(int bits) {
    return __builtin_bit_cast(h2v, bits);
}

__launch_bounds__(256)
__global__ void lstm_cls_kernel(const float* __restrict__ x,
                                const float* __restrict__ W_ih,
                                const float* __restrict__ W_hh,
                                const float* __restrict__ b_ih,
                                const float* __restrict__ b_hh,
                                const float* __restrict__ W_fc,
                                const float* __restrict__ b_fc,
                                float* __restrict__ out) {
    const int tid  = threadIdx.x;
    const int wave = tid >> 6;
    const int lane = tid & 63;
    const int b    = blockIdx.x * 4 + wave;   // one batch per wave
    const int j    = lane >> 2;               // hidden unit 0..15
    const int q    = lane & 3;                // 0=i, 1=f, 2=g, 3=o
    const int row  = q * 16 + j;              // row in [4H] (PyTorch order)

    const float LOG2E = 1.44269504088896340736f;
    const float NEG2L = -2.0f * LOG2E;
    const float NEG4L = -4.0f * LOG2E;
    // kk folded into weights: matvec emits kk*a; r = 1/(1+exp2(kk*a))
    // q!=2 -> sigmoid(a); q==2 -> (tanh(a)+1)/2
    const float kk = (q == 2) ? NEG2L : -LOG2E;

    // f16 weight pairs matching the h-pair pattern (k0, k0+2):
    // (0,2)(1,3)(4,6)(5,7)(8,10)(9,11)(12,14)(13,15)
    const float* wr = W_hh + row * 16;
    h2v wp0, wp1, wp2, wp3, wp4, wp5, wp6, wp7;
    {
        #define MKWP(WP, K0) \
            WP.x = (_Float16)(kk * wr[K0]); WP.y = (_Float16)(kk * wr[(K0) + 2]);
        MKWP(wp0, 0) MKWP(wp1, 1) MKWP(wp2, 4) MKWP(wp3, 5)
        MKWP(wp4, 8) MKWP(wp5, 9) MKWP(wp6, 12) MKWP(wp7, 13)
        #undef MKWP
    }

    const float kwih  = kk * W_ih[row];
    const float kbias = kk * (b_ih[row] + b_hh[row]);

    // Preload the wave's x sequence into 16 VGPRs
    const float4* xv = (const float4*)(x + (size_t)b * T_LEN);
    const float4 xq0 = xv[lane];
    const float4 xq1 = xv[lane + 64];
    const float4 xq2 = xv[lane + 128];
    const float4 xq3 = xv[lane + 192];

    float h  = 0.0f;
    float cs = 0.0f;   // cs = -2*log2e * c  (pre-scaled cell state)

    auto step = [&](float ax) {
        // (h_j, h_{j+-2}) f16 pair: partner via ROW_ROR:8, pack with pkrtz
        const float hr = movdpp<0x128>(h);
        const int hb = pack_rtz(h, hr);

        // q=0 source lanes: 0->(h0,h2) 4->(h1,h3) 16->(h4,h6) 20->(h5,h7)
        //                   32->(h8,h10) 36->(h9,h11) 48->(h12,h14) 52->(h13,h15)
        const int s0 = rlanei(hb, 0);
        const int s1 = rlanei(hb, 4);
        const int s2 = rlanei(hb, 16);
        const int s3 = rlanei(hb, 20);
        const int s4 = rlanei(hb, 32);
        const int s5 = rlanei(hb, 36);
        const int s6 = rlanei(hb, 48);
        const int s7 = rlanei(hb, 52);

        float A = fdot2(wp0, as_h2(s0), ax);
        float B = fdot2(wp1, as_h2(s1), 0.0f);
        A = fdot2(wp2, as_h2(s2), A);
        B = fdot2(wp3, as_h2(s3), B);
        A = fdot2(wp4, as_h2(s4), A);
        B = fdot2(wp5, as_h2(s5), B);
        A = fdot2(wp6, as_h2(s6), A);
        B = fdot2(wp7, as_h2(s7), B);
        const float sa = A + B;               // = kk * a_row

        const float r = frcp(1.0f + fexp2(sa));

        // quad gather (r0 = self; only q=0 lanes' h/cs are ever read)
        const float r1 = quad_bcastf<1>(r);   // f (sigmoid)
        const float r2 = quad_bcastf<2>(r);   // (tanh g + 1)/2
        const float r3 = quad_bcastf<3>(r);   // o (sigmoid)

        // cs = r1*cs + NEG2L*r*(2*r2-1) = fma(r1, cs, fma(m2, r2, -m))
        const float m  = NEG2L * r;           // DPP shadow
        const float m2 = NEG4L * r;           // DPP shadow
        const float term = fmaf(m2, r2, -m);
        cs = fmaf(r1, cs, term);              // cs = -2L * c

        // h = o*tanh(c) = 2*o/(1+exp2(cs)) - o
        const float et = fexp2(cs);
        const float rt = frcp(1.0f + et);
        const float t3 = r3 + r3;             // exp shadow
        h = fmaf(t3, rt, -r3);
    };

    #pragma unroll
    for (int k = 0; k < 4; ++k) {
        const float4 xk = (k == 0) ? xq0 : (k == 1) ? xq1
                        : (k == 2) ? xq2 : xq3;
        #pragma unroll 2
        for (int r = 0; r < 64; ++r) {
            // x front-end hoisted off the serial h-chain (h-independent)
            const float ax0 = fmaf(kwih, rlanef(xk.x, r), kbias);
            const float ax1 = fmaf(kwih, rlanef(xk.y, r), kbias);
            const float ax2 = fmaf(kwih, rlanef(xk.z, r), kbias);
            const float ax3 = fmaf(kwih, rlanef(xk.w, r), kbias);
            step(ax0);
            step(ax1);
            step(ax2);
            step(ax3);
        }
    }

    // Epilogue: logits[b, cc] = b_fc[cc] + sum_k W_fc[cc,k] * h_k
    float hv[16];
    #pragma unroll
    for (int k = 0; k < 16; ++k) hv[k] = rlanef(h, 4 * k);

    if (lane < 6) {
        const float* wf = W_fc + lane * 16;
        float acc = b_fc[lane];
        #pragma unroll
        for (int k = 0; k < 16; ++k) acc = fmaf(wf[k], hv[k], acc);
        out[b * 6 + lane] = acc;
    }
}

extern "C" void kernel_launch(void* const* d_in, const int* in_sizes, int n_in,
                              void* d_out, int out_size, void* d_ws, size_t ws_size,
                              hipStream_t stream) {
    const float* x    = (const float*)d_in[0];
    const float* W_ih = (const float*)d_in[1];
    const float* W_hh = (const float*)d_in[2];
    const float* b_ih = (const float*)d_in[3];
    const float* b_hh = (const float*)d_in[4];
    const float* W_fc = (const float*)d_in[5];
    const float* b_fc = (const float*)d_in[6];
    float* out = (float*)d_out;

    lstm_cls_kernel<<<BATCH / 4, 256, 0, stream>>>(x, W_ih, W_hh, b_ih, b_hh,
                                                   W_fc, b_fc, out);
}

// Round 8
// 155.956 us; speedup vs baseline: 1.0337x; 1.0048x over previous
//
#include <hip/hip_runtime.h>

// LSTMClassifier: B=1024, T=1024, H=16, C=6
// One wave per batch (1024 waves = 1/SIMD = max parallelism). Lane 4j+q owns
// gate q of hidden unit j. Pure latency-bound serial recurrence.
//  - matvec: h as f16 pairs, 8 readlane + 8 v_dot2_f32_f16, two 4-deep chains
//  - exp-split: exp2(A+B) = exp2(A)*exp2(B) -> the two chains feed exp2 in
//    parallel; serial add+exp replaced by mul (shorter critical path)
//  - front-end: ROW_ROR:8 partner + one v_cvt_pkrtz_f16_f32 pack
//  - kk folded into weights; cell state pre-scaled cs = -2*log2e*c
//  - x contribution (ax) hoisted per 4-step group: off the serial chain
// R6 lesson: 4-chain tree + unroll-4 regressed; R5/R7 2-chain unroll-2 shape.

#define T_LEN 1024
#define BATCH 1024

typedef _Float16 h2v __attribute__((ext_vector_type(2)));

__device__ __forceinline__ float rlanef(float v, int l) {
    return __int_as_float(__builtin_amdgcn_readlane(__float_as_int(v), l));
}
__device__ __forceinline__ int rlanei(int v, int l) {
    return __builtin_amdgcn_readlane(v, l);
}

template<int CTRL>
__device__ __forceinline__ float movdpp(float v) {
    return __int_as_float(
        __builtin_amdgcn_mov_dpp(__float_as_int(v), CTRL, 0xf, 0xf, true));
}

template<int N>
__device__ __forceinline__ float quad_bcastf(float v) {
    constexpr int ctrl = N * 0x55;  // replicate lane N of each quad
    return __int_as_float(
        __builtin_amdgcn_mov_dpp(__float_as_int(v), ctrl, 0xf, 0xf, true));
}

__device__ __forceinline__ float fexp2(float x) {
#if __has_builtin(__builtin_amdgcn_exp2f)
    return __builtin_amdgcn_exp2f(x);
#else
    return exp2f(x);
#endif
}
__device__ __forceinline__ float frcp(float x) {
#if __has_builtin(__builtin_amdgcn_rcpf)
    return __builtin_amdgcn_rcpf(x);
#else
    return 1.0f / x;
#endif
}

__device__ __forceinline__ float fdot2(h2v a, h2v b, float c) {
#if __has_builtin(__builtin_amdgcn_fdot2)
    return __builtin_amdgcn_fdot2(a, b, c, false);
#else
    return fmaf((float)a.x, (float)b.x, fmaf((float)a.y, (float)b.y, c));
#endif
}

__device__ __forceinline__ int pack_rtz(float lo, float hi) {
#if __has_builtin(__builtin_amdgcn_cvt_pkrtz)
    return __builtin_bit_cast(int, __builtin_amdgcn_cvt_pkrtz(lo, hi));
#else
    h2v p; p.x = (_Float16)lo; p.y = (_Float16)hi;
    return __builtin_bit_cast(int, p);
#endif
}

__device__ __forceinline__ h2v as_h2(int bits) {
    return __builtin_bit_cast(h2v, bits);
}

__launch_bounds__(256)
__global__ void lstm_cls_kernel(const float* __restrict__ x,
                                const float* __restrict__ W_ih,
                                const float* __restrict__ W_hh,
                                const float* __restrict__ b_ih,
                                const float* __restrict__ b_hh,
                                const float* __restrict__ W_fc,
                                const float* __restrict__ b_fc,
                                float* __restrict__ out) {
    const int tid  = threadIdx.x;
    const int wave = tid >> 6;
    const int lane = tid & 63;
    const int b    = blockIdx.x * 4 + wave;   // one batch per wave
    const int j    = lane >> 2;               // hidden unit 0..15
    const int q    = lane & 3;                // 0=i, 1=f, 2=g, 3=o
    const int row  = q * 16 + j;              // row in [4H] (PyTorch order)

    const float LOG2E = 1.44269504088896340736f;
    const float NEG2L = -2.0f * LOG2E;
    const float NEG4L = -4.0f * LOG2E;
    // kk folded into weights: matvec emits kk*a; r = 1/(1+exp2(kk*a))
    // q!=2 -> sigmoid(a); q==2 -> (tanh(a)+1)/2
    const float kk = (q == 2) ? NEG2L : -LOG2E;

    // f16 weight pairs matching the h-pair pattern (k0, k0+2):
    // (0,2)(1,3)(4,6)(5,7)(8,10)(9,11)(12,14)(13,15)
    const float* wr = W_hh + row * 16;
    h2v wp0, wp1, wp2, wp3, wp4, wp5, wp6, wp7;
    {
        #define MKWP(WP, K0) \
            WP.x = (_Float16)(kk * wr[K0]); WP.y = (_Float16)(kk * wr[(K0) + 2]);
        MKWP(wp0, 0) MKWP(wp1, 1) MKWP(wp2, 4) MKWP(wp3, 5)
        MKWP(wp4, 8) MKWP(wp5, 9) MKWP(wp6, 12) MKWP(wp7, 13)
        #undef MKWP
    }

    const float kwih  = kk * W_ih[row];
    const float kbias = kk * (b_ih[row] + b_hh[row]);

    // Preload the wave's x sequence into 16 VGPRs
    const float4* xv = (const float4*)(x + (size_t)b * T_LEN);
    const float4 xq0 = xv[lane];
    const float4 xq1 = xv[lane + 64];
    const float4 xq2 = xv[lane + 128];
    const float4 xq3 = xv[lane + 192];

    float h  = 0.0f;
    float cs = 0.0f;   // cs = -2*log2e * c  (pre-scaled cell state)

    auto step = [&](float ax) {
        // (h_j, h_{j+-2}) f16 pair: partner via ROW_ROR:8, pack with pkrtz
        const float hr = movdpp<0x128>(h);
        const int hb = pack_rtz(h, hr);

        // q=0 source lanes: 0->(h0,h2) 4->(h1,h3) 16->(h4,h6) 20->(h5,h7)
        //                   32->(h8,h10) 36->(h9,h11) 48->(h12,h14) 52->(h13,h15)
        const int s0 = rlanei(hb, 0);
        const int s1 = rlanei(hb, 4);
        const int s2 = rlanei(hb, 16);
        const int s3 = rlanei(hb, 20);
        const int s4 = rlanei(hb, 32);
        const int s5 = rlanei(hb, 36);
        const int s6 = rlanei(hb, 48);
        const int s7 = rlanei(hb, 52);

        float A = fdot2(wp0, as_h2(s0), ax);
        float B = fdot2(wp1, as_h2(s1), 0.0f);
        A = fdot2(wp2, as_h2(s2), A);
        B = fdot2(wp3, as_h2(s3), B);
        A = fdot2(wp4, as_h2(s4), A);
        B = fdot2(wp5, as_h2(s5), B);
        A = fdot2(wp6, as_h2(s6), A);
        B = fdot2(wp7, as_h2(s7), B);

        // exp-split: exp2(A+B) = exp2(A)*exp2(B); the two chains feed the
        // trans pipe independently, serial add removed from critical path
        const float eA = fexp2(A);
        const float eB = fexp2(B);
        const float e  = eA * eB;
        const float r  = frcp(1.0f + e);

        // quad gather (r0 = self; only q=0 lanes' h/cs are ever read)
        const float r1 = quad_bcastf<1>(r);   // f (sigmoid)
        const float r2 = quad_bcastf<2>(r);   // (tanh g + 1)/2
        const float r3 = quad_bcastf<3>(r);   // o (sigmoid)

        // cs = r1*cs + NEG2L*r*(2*r2-1) = fma(r1, cs, fma(m2, r2, -m))
        const float m  = NEG2L * r;           // DPP shadow
        const float m2 = NEG4L * r;           // DPP shadow
        const float term = fmaf(m2, r2, -m);
        cs = fmaf(r1, cs, term);              // cs = -2L * c

        // h = o*tanh(c) = 2*o/(1+exp2(cs)) - o
        const float et = fexp2(cs);
        const float rt = frcp(1.0f + et);
        const float t3 = r3 + r3;             // exp shadow
        h = fmaf(t3, rt, -r3);
    };

    #pragma unroll
    for (int k = 0; k < 4; ++k) {
        const float4 xk = (k == 0) ? xq0 : (k == 1) ? xq1
                        : (k == 2) ? xq2 : xq3;
        #pragma unroll 2
        for (int r = 0; r < 64; ++r) {
            // x front-end hoisted off the serial h-chain (h-independent)
            const float ax0 = fmaf(kwih, rlanef(xk.x, r), kbias);
            const float ax1 = fmaf(kwih, rlanef(xk.y, r), kbias);
            const float ax2 = fmaf(kwih, rlanef(xk.z, r), kbias);
            const float ax3 = fmaf(kwih, rlanef(xk.w, r), kbias);
            step(ax0);
            step(ax1);
            step(ax2);
            step(ax3);
        }
    }

    // Epilogue: logits[b, cc] = b_fc[cc] + sum_k W_fc[cc,k] * h_k
    float hv[16];
    #pragma unroll
    for (int k = 0; k < 16; ++k) hv[k] = rlanef(h, 4 * k);

    if (lane < 6) {
        const float* wf = W_fc + lane * 16;
        float acc = b_fc[lane];
        #pragma unroll
        for (int k = 0; k < 16; ++k) acc = fmaf(wf[k], hv[k], acc);
        out[b * 6 + lane] = acc;
    }
}

extern "C" void kernel_launch(void* const* d_in, const int* in_sizes, int n_in,
                              void* d_out, int out_size, void* d_ws, size_t ws_size,
                              hipStream_t stream) {
    const float* x    = (const float*)d_in[0];
    const float* W_ih = (const float*)d_in[1];
    const float* W_hh = (const float*)d_in[2];
    const float* b_ih = (const float*)d_in[3];
    const float* b_hh = (const float*)d_in[4];
    const float* W_fc = (const float*)d_in[5];
    const float* b_fc = (const float*)d_in[6];
    float* out = (float*)d_out;

    lstm_cls_kernel<<<BATCH / 4, 256, 0, stream>>>(x, W_ih, W_hh, b_ih, b_hh,
                                                   W_fc, b_fc, out);
}